// Round 1
// baseline (1028.384 us; speedup 1.0000x reference)
//
#include <hip/hip_runtime.h>
#include <cmath>

#define BB 128
#define TT 4096
#define NN 48

typedef float v2f __attribute__((ext_vector_type(2)));

__device__ __forceinline__ float wave_reduce_sum(float v) {
  #pragma unroll
  for (int m = 32; m >= 1; m >>= 1) v += __shfl_xor(v, m, 64);
  return v;
}
__device__ __forceinline__ float wave_reduce_max(float v) {
  #pragma unroll
  for (int m = 32; m >= 1; m >>= 1) v = fmaxf(v, __shfl_xor(v, m, 64));
  return v;
}

// One block (one wave) per batch element. Lane j owns state P[j] (linear-domain
// scaled forward variable) and column j of E = exp(transitions) * (1/48).
// Recursion per step: s[j] = sum_i P[i]*E[i][j]  (LDS broadcast matvec),
//                     P'[j] = s[j] * exp(em[t][j]).
// The 1/48 folded into E keeps P ~O(1); exact bookkeeping 4095*ln(48f) at end.
__launch_bounds__(64, 1)
__global__ void crf_nll_kernel(const float* __restrict__ em,
                               const float* __restrict__ trans,
                               const float* __restrict__ startv,
                               const float* __restrict__ endv,
                               const int* __restrict__ tags,
                               float* __restrict__ out) {
  const int b = blockIdx.x;
  const int j = threadIdx.x;
  const int jc = (j < NN) ? j : (NN - 1);

  __shared__ __align__(16) float pbuf[2][64];

  const float FSCALE = 1.0f / 48.0f;

  // E column j in registers, as 24 float2 pairs (paired over i).
  v2f Ec[NN / 2];
  #pragma unroll
  for (int i = 0; i < NN / 2; ++i) {
    float e0 = __expf(trans[(2 * i + 0) * NN + jc]) * FSCALE;
    float e1 = __expf(trans[(2 * i + 1) * NN + jc]) * FSCALE;
    v2f e; e.x = e0; e.y = e1;
    Ec[i] = e;
  }

  const float* emb  = em + (size_t)b * TT * NN;   // this batch's emissions
  const float* embr = emb + jc;                   // lane's column within a row

  // t = 0 init: alpha0 = start + em0 ; P = exp(alpha0), lanes >=48 mirror lane 47
  float P = (j < NN) ? __expf(startv[jc] + embr[0]) : 0.0f;

  // 4-deep emission-row prefetch (named registers; never runtime-indexed)
  float pf0 = embr[(size_t)1 * NN];
  float pf1 = embr[(size_t)2 * NN];
  float pf2 = embr[(size_t)3 * NN];
  float pf3 = embr[(size_t)4 * NN];

  int ikacc = 0;  // accumulated power-of-2 renorm exponents (exact)

  #define STEP(PF, BUFIDX, NEXT_T) do {                                   \
    float w = __expf(PF);                                                 \
    int nt_ = (NEXT_T) > (TT - 1) ? (TT - 1) : (NEXT_T);                  \
    PF = embr[(size_t)nt_ * NN];                                          \
    pbuf[BUFIDX][j] = P;                                                  \
    __syncthreads();                                                      \
    const float4* p4_ = (const float4*)pbuf[BUFIDX];                      \
    v2f a0_; a0_.x = 0.f; a0_.y = 0.f;                                    \
    v2f a1_ = a0_;                                                        \
    _Pragma("unroll")                                                     \
    for (int k_ = 0; k_ < NN / 4; ++k_) {                                 \
      float4 v_ = p4_[k_];                                                \
      v2f plo_; plo_.x = v_.x; plo_.y = v_.y;                             \
      v2f phi_; phi_.x = v_.z; phi_.y = v_.w;                             \
      a0_ = __builtin_elementwise_fma(plo_, Ec[2 * k_ + 0], a0_);         \
      a1_ = __builtin_elementwise_fma(phi_, Ec[2 * k_ + 1], a1_);         \
    }                                                                     \
    float s_ = (a0_.x + a0_.y) + (a1_.x + a1_.y);                         \
    P = s_ * w;                                                           \
  } while (0)

  // steady state: 1023 iterations x 4 steps = t = 1 .. 4092
  int t = 1;
  #pragma unroll 1
  for (int it = 0; it < 1023; ++it) {
    STEP(pf0, 1, t + 4);
    STEP(pf1, 0, t + 5);
    STEP(pf2, 1, t + 6);
    STEP(pf3, 0, t + 7);
    t += 4;
    if ((it & 127) == 127) {
      // safety renorm: exact power-of-2 rescale
      float pm = (j < NN) ? P : 0.0f;
      pm = wave_reduce_max(pm);
      int e_;
      (void)frexpf(pm, &e_);
      P = ldexpf(P, -e_);
      ikacc += e_;
    }
  }
  // tail: t = 4093, 4094, 4095
  STEP(pf0, 1, TT - 1);
  STEP(pf1, 0, TT - 1);
  STEP(pf2, 1, TT - 1);
  #undef STEP

  // log Z = ln( sum_j P[j] * exp(end[j]) ) + 4095*ln(48f) + ikacc*ln2
  float endj = __expf(endv[jc]);
  float Sv = (j < NN) ? P * endj : 0.0f;
  float S = wave_reduce_sum(Sv);

  // ---- gold path score: all 64 lanes stride over T ----
  const int* tgb = tags + (size_t)b * TT;
  float sc = 0.0f;
  for (int tt = j; tt < TT; tt += 64) {
    int tg = tgb[tt];
    sc += emb[(size_t)tt * NN + tg];
    if (tt > 0) {
      int tgp = tgb[tt - 1];
      sc += trans[tgp * NN + tg];
    }
  }
  sc = wave_reduce_sum(sc);

  if (j == 0) {
    double K = -log((double)FSCALE);           // exact -ln(float(1/48))
    double logZ = (double)__logf(S)
                + (double)ikacc * 0.6931471805599453
                + 4095.0 * K;
    double score = (double)sc + (double)startv[tgb[0]] + (double)endv[tgb[TT - 1]];
    out[b] = (float)(logZ - score);
  }
}

extern "C" void kernel_launch(void* const* d_in, const int* in_sizes, int n_in,
                              void* d_out, int out_size, void* d_ws, size_t ws_size,
                              hipStream_t stream) {
  const float* em     = (const float*)d_in[0];
  const float* trans  = (const float*)d_in[1];
  const float* startv = (const float*)d_in[2];
  const float* endv   = (const float*)d_in[3];
  const int*   tags   = (const int*)d_in[4];
  float* out = (float*)d_out;

  hipLaunchKernelGGL(crf_nll_kernel, dim3(BB), dim3(64), 0, stream,
                     em, trans, startv, endv, tags, out);
}

// Round 2
// 759.032 us; speedup vs baseline: 1.3549x; 1.3549x over previous
//
#include <hip/hip_runtime.h>
#include <cmath>

#define BB 128
#define TT 4096
#define NN 48

__device__ __forceinline__ float wave_reduce_sum(float v) {
  #pragma unroll
  for (int m = 32; m >= 1; m >>= 1) v += __shfl_xor(v, m, 64);
  return v;
}
__device__ __forceinline__ float wave_reduce_max(float v) {
  #pragma unroll
  for (int m = 32; m >= 1; m >>= 1) v = fmaxf(v, __shfl_xor(v, m, 64));
  return v;
}

__device__ __forceinline__ float lane_bcast(float x, int lane) {
  return __uint_as_float(__builtin_amdgcn_readlane(__float_as_uint(x), lane));
}

// One block (one wave) per batch element. Lane j owns state P[j] (linear-domain
// scaled forward variable) and column j of E = exp(transitions) * (1/48).
// Recursion per step: s[j] = sum_i P[i]*E[i][j], done entirely in-register via
// v_readlane broadcast (no LDS, no barrier):
//   s += readlane(P, i) * Ec[i]   (48 readlanes + 48 FMAs, 4 acc chains)
// then P'[j] = s[j] * exp(em[t][j]). 1/48 folded into E keeps P ~O(1);
// exact bookkeeping 4095*ln(48f) at end.
__launch_bounds__(64, 1)
__global__ void crf_nll_kernel(const float* __restrict__ em,
                               const float* __restrict__ trans,
                               const float* __restrict__ startv,
                               const float* __restrict__ endv,
                               const int* __restrict__ tags,
                               float* __restrict__ out) {
  const int b = blockIdx.x;
  const int j = threadIdx.x;
  const int jc = (j < NN) ? j : (NN - 1);

  const float FSCALE = 1.0f / 48.0f;

  // E column j in registers: Ec[i] = exp(trans[i][jc]) / 48
  float Ec[NN];
  #pragma unroll
  for (int i = 0; i < NN; ++i) {
    Ec[i] = __expf(trans[i * NN + jc]) * FSCALE;
  }

  const float* emb  = em + (size_t)b * TT * NN;   // this batch's emissions
  const float* embr = emb + jc;                   // lane's column within a row

  // t = 0 init: alpha0 = start + em0 ; P = exp(alpha0). Lanes >=48 mirror 47.
  float P = __expf(startv[jc] + embr[0]);

  // 4-deep emission-row prefetch (named registers; never runtime-indexed)
  float pf0 = embr[(size_t)1 * NN];
  float pf1 = embr[(size_t)2 * NN];
  float pf2 = embr[(size_t)3 * NN];
  float pf3 = embr[(size_t)4 * NN];

  int ikacc = 0;  // accumulated power-of-2 renorm exponents (exact)

  #define STEP(PF, NEXT_T) do {                                           \
    float w_ = __expf(PF);                                                \
    int nt_ = (NEXT_T) > (TT - 1) ? (TT - 1) : (NEXT_T);                  \
    PF = embr[(size_t)nt_ * NN];                                          \
    float s0_ = 0.f, s1_ = 0.f, s2_ = 0.f, s3_ = 0.f;                     \
    _Pragma("unroll")                                                     \
    for (int i_ = 0; i_ < NN; i_ += 4) {                                  \
      s0_ = fmaf(lane_bcast(P, i_ + 0), Ec[i_ + 0], s0_);                 \
      s1_ = fmaf(lane_bcast(P, i_ + 1), Ec[i_ + 1], s1_);                 \
      s2_ = fmaf(lane_bcast(P, i_ + 2), Ec[i_ + 2], s2_);                 \
      s3_ = fmaf(lane_bcast(P, i_ + 3), Ec[i_ + 3], s3_);                 \
    }                                                                     \
    P = ((s0_ + s1_) + (s2_ + s3_)) * w_;                                 \
  } while (0)

  // steady state: 1023 iterations x 4 steps = t = 1 .. 4092
  int t = 1;
  #pragma unroll 1
  for (int it = 0; it < 1023; ++it) {
    STEP(pf0, t + 4);
    STEP(pf1, t + 5);
    STEP(pf2, t + 6);
    STEP(pf3, t + 7);
    t += 4;
    if ((it & 127) == 127) {
      // safety renorm: exact power-of-2 rescale
      float pm = wave_reduce_max(P);
      int e_;
      (void)frexpf(pm, &e_);
      P = ldexpf(P, -e_);
      ikacc += e_;
    }
  }
  // tail: t = 4093, 4094, 4095
  STEP(pf0, TT - 1);
  STEP(pf1, TT - 1);
  STEP(pf2, TT - 1);
  #undef STEP

  // log Z = ln( sum_j P[j] * exp(end[j]) ) + 4095*ln(48f) + ikacc*ln2
  float endj = __expf(endv[jc]);
  float Sv = (j < NN) ? P * endj : 0.0f;
  float S = wave_reduce_sum(Sv);

  // ---- gold path score: all 64 lanes stride over T ----
  const int* tgb = tags + (size_t)b * TT;
  float sc = 0.0f;
  for (int tt = j; tt < TT; tt += 64) {
    int tg = tgb[tt];
    sc += emb[(size_t)tt * NN + tg];
    if (tt > 0) {
      int tgp = tgb[tt - 1];
      sc += trans[tgp * NN + tg];
    }
  }
  sc = wave_reduce_sum(sc);

  if (j == 0) {
    double K = -log((double)FSCALE);           // exact -ln(float(1/48))
    double logZ = (double)__logf(S)
                + (double)ikacc * 0.6931471805599453
                + 4095.0 * K;
    double score = (double)sc + (double)startv[tgb[0]] + (double)endv[tgb[TT - 1]];
    out[b] = (float)(logZ - score);
  }
}

extern "C" void kernel_launch(void* const* d_in, const int* in_sizes, int n_in,
                              void* d_out, int out_size, void* d_ws, size_t ws_size,
                              hipStream_t stream) {
  const float* em     = (const float*)d_in[0];
  const float* trans  = (const float*)d_in[1];
  const float* startv = (const float*)d_in[2];
  const float* endv   = (const float*)d_in[3];
  const int*   tags   = (const int*)d_in[4];
  float* out = (float*)d_out;

  hipLaunchKernelGGL(crf_nll_kernel, dim3(BB), dim3(64), 0, stream,
                     em, trans, startv, endv, tags, out);
}

// Round 3
// 278.543 us; speedup vs baseline: 3.6920x; 2.7250x over previous
//
#include <hip/hip_runtime.h>
#include <cmath>

#define BB 128
#define TT 4096
#define NN 48
#define NCHUNK 16
#define CHUNKLEN 256

typedef short bf16x8 __attribute__((ext_vector_type(8)));
typedef float f32x4 __attribute__((ext_vector_type(4)));
typedef int   i32x4 __attribute__((ext_vector_type(4)));

__device__ __forceinline__ float wave_reduce_sum(float v) {
  #pragma unroll
  for (int m = 32; m >= 1; m >>= 1) v += __shfl_xor(v, m, 64);
  return v;
}
__device__ __forceinline__ int bperm(int idx, int src) {
  return __builtin_amdgcn_ds_bpermute(idx, src);
}
__device__ __forceinline__ float lane_bcast(float x, int lane) {
  return __uint_as_float((unsigned)__builtin_amdgcn_readlane(__float_as_int(x), lane));
}
__device__ __forceinline__ int cvt_pk_bf16(float lo, float hi) {
  int r;
  asm("v_cvt_pk_bf16_f32 %0, %1, %2" : "=v"(r) : "v"(lo), "v"(hi));
  return r;
}
__device__ __forceinline__ unsigned short f2bf(float f) {  // RNE f32->bf16
  unsigned u = __float_as_uint(f);
  unsigned r = (u + 0x7FFFu + ((u >> 16) & 1u)) >> 16;
  return (unsigned short)r;
}

// ---------------- Phase 1: per-(batch,chunk) transition-matrix product ----
// One wave per (b, chunk). Computes G_c = Prod_{t in chunk} M_t, M_t = E diag(w_t),
// E = exp(trans)/48, w_t = exp(em[t]). Works on Y = X^T so the step is
//   Y <- diag(w_t) * E^T * Y
// with E^T the FIXED MFMA A-operand and Y chained as the B-operand.
// C-frag (row=(l>>4)*4+reg, col=l&15) -> next B-frag (k=(l>>4)*8+e, col=l&15)
// via cvt_pk pairs + ds_bpermute (src lane = 32*(gB&1)+16*(q>>1)+c; q even->pk0).
// Result stored as G row-major bf16 [48][48] (G[i][j] = Y[j][i]).
__launch_bounds__(64, 2)
__global__ void crf_chunk_kernel(const float* __restrict__ em,
                                 const float* __restrict__ trans,
                                 unsigned short* __restrict__ ws) {
  const int blk = blockIdx.x;
  const int b = blk >> 4;
  const int c = blk & (NCHUNK - 1);
  const int l = threadIdx.x;
  const int g = l >> 4;
  const int rr = l & 15;
  const int jc = (l < NN) ? l : (NN - 1);

  const float FSCALE = 1.0f / 48.0f;

  // A = E^T padded to [48 x 64] (zero cols k>=48), frags Af[mt][kt]
  // A[i][k] = E[k][i] = exp(trans[k*48+i])/48
  bf16x8 Af[3][2];
  #pragma unroll
  for (int mt = 0; mt < 3; ++mt)
  #pragma unroll
  for (int kt = 0; kt < 2; ++kt) {
    bf16x8 a;
    #pragma unroll
    for (int e = 0; e < 8; ++e) {
      int k = kt * 32 + g * 8 + e;
      int i = mt * 16 + rr;
      float v = (k < NN) ? __expf(trans[k * NN + i]) * FSCALE : 0.0f;
      a[e] = (short)f2bf(v);
    }
    Af[mt][kt] = a;
  }

  // B = Y = Identity. B[k][col] frag: lane l elem e -> k=kt*32+g*8+e, col=ct*16+rr
  i32x4 Bi[2][3];
  #pragma unroll
  for (int kt = 0; kt < 2; ++kt)
  #pragma unroll
  for (int ct = 0; ct < 3; ++ct) {
    i32x4 q;
    #pragma unroll
    for (int qi = 0; qi < 4; ++qi) {
      int k0  = kt * 32 + g * 8 + 2 * qi;
      int col = ct * 16 + rr;
      int lo = (k0     == col) ? 0x3F80 : 0;
      int hi = (k0 + 1 == col) ? 0x3F80 : 0;
      q[qi] = lo | (hi << 16);
    }
    Bi[kt][ct] = q;
  }

  const int idxA  = ((l >> 4) & 1) * 128 + (l & 15) * 4;  // byte addr of src lane
  const int idxB  = idxA + 64;
  const int wbase = (l >> 4) << 4;                        // 4*(4g)

  const float* embr = em + (size_t)b * TT * NN + jc;

  const int t0 = c * CHUNKLEN + 1;
  const int count = (c == NCHUNK - 1) ? (CHUNKLEN - 1) : CHUNKLEN;

  float pf0 = embr[(size_t)(t0 + 0) * NN];
  float pf1 = embr[(size_t)(t0 + 1) * NN];
  float pf2 = embr[(size_t)(t0 + 2) * NN];
  float pf3 = embr[(size_t)(t0 + 3) * NN];

  #define STEP(PF, NEXT_T) do {                                             \
    float w_ = __expf(PF);                                                  \
    int nt_ = (NEXT_T) > (TT - 1) ? (TT - 1) : (NEXT_T);                    \
    PF = embr[(size_t)nt_ * NN];                                            \
    int wi_ = __float_as_int(w_);                                           \
    float wb_[3][4];                                                        \
    _Pragma("unroll") for (int mt = 0; mt < 3; ++mt)                        \
    _Pragma("unroll") for (int r = 0; r < 4; ++r)                           \
      wb_[mt][r] = __uint_as_float(                                         \
          (unsigned)bperm(wbase + mt * 64 + r * 4, wi_));                   \
    f32x4 acc_[3][3];                                                       \
    _Pragma("unroll") for (int mt = 0; mt < 3; ++mt)                        \
    _Pragma("unroll") for (int nt = 0; nt < 3; ++nt) {                      \
      f32x4 z = {0.f, 0.f, 0.f, 0.f};                                       \
      z = __builtin_amdgcn_mfma_f32_16x16x32_bf16(                          \
            Af[mt][0], __builtin_bit_cast(bf16x8, Bi[0][nt]), z, 0, 0, 0);  \
      z = __builtin_amdgcn_mfma_f32_16x16x32_bf16(                          \
            Af[mt][1], __builtin_bit_cast(bf16x8, Bi[1][nt]), z, 0, 0, 0);  \
      acc_[mt][nt] = z;                                                     \
    }                                                                       \
    int pk0_[3][3], pk1_[3][3];                                             \
    _Pragma("unroll") for (int mt = 0; mt < 3; ++mt)                        \
    _Pragma("unroll") for (int nt = 0; nt < 3; ++nt) {                      \
      pk0_[mt][nt] = cvt_pk_bf16(acc_[mt][nt][0] * wb_[mt][0],              \
                                 acc_[mt][nt][1] * wb_[mt][1]);             \
      pk1_[mt][nt] = cvt_pk_bf16(acc_[mt][nt][2] * wb_[mt][2],              \
                                 acc_[mt][nt][3] * wb_[mt][3]);             \
    }                                                                       \
    _Pragma("unroll") for (int ct = 0; ct < 3; ++ct) {                      \
      int s0 = (l < 32) ? pk0_[0][ct] : pk0_[1][ct];                        \
      int s1 = (l < 32) ? pk1_[0][ct] : pk1_[1][ct];                        \
      i32x4 b0, b1;                                                         \
      b0[0] = bperm(idxA, s0);          b0[1] = bperm(idxA, s1);            \
      b0[2] = bperm(idxB, s0);          b0[3] = bperm(idxB, s1);            \
      b1[0] = bperm(idxA, pk0_[2][ct]); b1[1] = bperm(idxA, pk1_[2][ct]);   \
      b1[2] = bperm(idxB, pk0_[2][ct]); b1[3] = bperm(idxB, pk1_[2][ct]);   \
      Bi[0][ct] = b0; Bi[1][ct] = b1;                                       \
    }                                                                       \
  } while (0)

  int t = t0;
  #pragma unroll 1
  for (int it = 0; it < count / 4; ++it) {
    STEP(pf0, t + 4);
    STEP(pf1, t + 5);
    STEP(pf2, t + 6);
    STEP(pf3, t + 7);
    t += 4;
  }
  if (count & 3) {  // last chunk: 3 remaining steps
    STEP(pf0, TT - 1);
    STEP(pf1, TT - 1);
    STEP(pf2, TT - 1);
  }
  #undef STEP

  // Store G = X = Y^T, row-major bf16 [48][48]:
  // Bi[kt][ct] lane l = Y[kt*32+8g+2q(+1)][ct*16+rr] = X[i=ct*16+rr][j=kt*32+8g+2q]
  unsigned short* Gc = ws + (size_t)(b * NCHUNK + c) * (NN * NN);
  #pragma unroll
  for (int kt = 0; kt < 2; ++kt)
  #pragma unroll
  for (int ct = 0; ct < 3; ++ct) {
    if (kt == 0 || g < 2) {  // skip padded k rows 48..63
      int i = ct * 16 + rr;
      int j = kt * 32 + g * 8;
      *(i32x4*)(Gc + i * NN + j) = Bi[kt][ct];
    }
  }
}

// ---------------- Phase 2: combine chunk products + gold score ------------
__launch_bounds__(64, 1)
__global__ void crf_combine_kernel(const float* __restrict__ em,
                                   const float* __restrict__ trans,
                                   const float* __restrict__ startv,
                                   const float* __restrict__ endv,
                                   const int* __restrict__ tags,
                                   const unsigned short* __restrict__ ws,
                                   float* __restrict__ out) {
  const int b = blockIdx.x;
  const int l = threadIdx.x;
  const int jc = (l < NN) ? l : (NN - 1);

  const float* emb = em + (size_t)b * TT * NN;
  const float FSCALE = 1.0f / 48.0f;

  // r = v0 = exp(start + em[0]); lanes >=48 mirror lane 47 (never summed)
  float r = __expf(startv[jc] + emb[jc]);

  #pragma unroll 1
  for (int c = 0; c < NCHUNK; ++c) {
    const unsigned short* Gc = ws + (size_t)(b * NCHUNK + c) * (NN * NN);
    float s0 = 0.f, s1 = 0.f, s2 = 0.f, s3 = 0.f;
    #pragma unroll
    for (int i = 0; i < NN; i += 4) {
      float g0 = __uint_as_float(((unsigned)Gc[(i + 0) * NN + jc]) << 16);
      float g1 = __uint_as_float(((unsigned)Gc[(i + 1) * NN + jc]) << 16);
      float g2 = __uint_as_float(((unsigned)Gc[(i + 2) * NN + jc]) << 16);
      float g3 = __uint_as_float(((unsigned)Gc[(i + 3) * NN + jc]) << 16);
      s0 = fmaf(lane_bcast(r, i + 0), g0, s0);
      s1 = fmaf(lane_bcast(r, i + 1), g1, s1);
      s2 = fmaf(lane_bcast(r, i + 2), g2, s2);
      s3 = fmaf(lane_bcast(r, i + 3), g3, s3);
    }
    r = (s0 + s1) + (s2 + s3);
  }

  float S = wave_reduce_sum((l < NN) ? r * __expf(endv[jc]) : 0.0f);

  // gold path score
  const int* tgb = tags + (size_t)b * TT;
  float sc = 0.0f;
  for (int tt = l; tt < TT; tt += 64) {
    int tg = tgb[tt];
    sc += emb[(size_t)tt * NN + tg];
    if (tt > 0) {
      int tgp = tgb[tt - 1];
      sc += trans[tgp * NN + tg];
    }
  }
  sc = wave_reduce_sum(sc);

  if (l == 0) {
    double K = -log((double)FSCALE);  // exact -ln(float(1/48))
    double logZ = log((double)S) + 4095.0 * K;
    double score = (double)sc + (double)startv[tgb[0]] + (double)endv[tgb[TT - 1]];
    out[b] = (float)(logZ - score);
  }
}

extern "C" void kernel_launch(void* const* d_in, const int* in_sizes, int n_in,
                              void* d_out, int out_size, void* d_ws, size_t ws_size,
                              hipStream_t stream) {
  const float* em     = (const float*)d_in[0];
  const float* trans  = (const float*)d_in[1];
  const float* startv = (const float*)d_in[2];
  const float* endv   = (const float*)d_in[3];
  const int*   tags   = (const int*)d_in[4];
  float* out = (float*)d_out;
  unsigned short* ws = (unsigned short*)d_ws;

  hipLaunchKernelGGL(crf_chunk_kernel, dim3(BB * NCHUNK), dim3(64), 0, stream,
                     em, trans, ws);
  hipLaunchKernelGGL(crf_combine_kernel, dim3(BB), dim3(64), 0, stream,
                     em, trans, startv, endv, tags, ws, out);
}

// Round 4
// 141.392 us; speedup vs baseline: 7.2733x; 1.9700x over previous
//
#include <hip/hip_runtime.h>
#include <cmath>

#define BB 128
#define TT 4096
#define NN 48

typedef short bf16x8 __attribute__((ext_vector_type(8)));
typedef float f32x4 __attribute__((ext_vector_type(4)));
typedef float v2f   __attribute__((ext_vector_type(2)));
typedef int   i32x4 __attribute__((ext_vector_type(4)));
typedef int   i32x2 __attribute__((ext_vector_type(2)));

__device__ __forceinline__ float wave_reduce_sum(float v) {
  #pragma unroll
  for (int m = 32; m >= 1; m >>= 1) v += __shfl_xor(v, m, 64);
  return v;
}
__device__ __forceinline__ int bperm(int byteidx, int src) {
  return __builtin_amdgcn_ds_bpermute(byteidx, src);
}
__device__ __forceinline__ float lane_bcast(float x, int lane) {
  return __uint_as_float((unsigned)__builtin_amdgcn_readlane(__float_as_int(x), lane));
}
__device__ __forceinline__ int cvt_pk_bf16(float lo, float hi) {
  int r;
  asm("v_cvt_pk_bf16_f32 %0, %1, %2" : "=v"(r) : "v"(lo), "v"(hi));
  return r;
}
__device__ __forceinline__ unsigned short f2bf(float f) {  // RNE f32->bf16
  unsigned u = __float_as_uint(f);
  unsigned r = (u + 0x7FFFu + ((u >> 16) & 1u)) >> 16;
  return (unsigned short)r;
}

// ---------------- Phase 1: per-(batch,chunk) transition-matrix product ----
// One wave per (b,c). Chain Y <- diag(w_t) * E^T * Y  (Y as MFMA B-operand,
// static A = E^T/48). KEY TRICK: relabel MFMA K-space so the C-fragment's
// packed bf16 words ARE the next B-operand verbatim (zero cross-lane moves):
//   B-slot (g, e) carries logical row phi(8g+e) = 16*(e>>2) + 4g + (e&3)
// for the K=0..31 tile, and 32+4g+e (e<4; e>=4 dummy, A=0 there) for the
// K=32..63 tile. C layout (m89): col=l&15, row=(l>>4)*4+reg -> pk words
// pk0=(rows 4g,4g+1), pk1=(rows 4g+2,4g+3) per 16-row tile mt. Under phi,
// B dwords per nt are exactly {pk0[0],pk1[0],pk0[1],pk1[1]} and
// {pk0[2],pk1[2],0,0}. The static A is BUILT with the same phi (free).
// Per-step DS: only 12 w-broadcast bpermutes. Also computes this chunk's
// gold-score slice. Stores G[i][j] = Y[j][i] row-major bf16 (rows coalesced
// for the combine kernel).
template<int NC, int CL>
__launch_bounds__(64, 2)
__global__ void crf_chunk_kernel(const float* __restrict__ em,
                                 const float* __restrict__ trans,
                                 const int* __restrict__ tags,
                                 unsigned short* __restrict__ G,
                                 float* __restrict__ sc_part) {
  const int blk = blockIdx.x;
  const int b = blk / NC;
  const int c = blk % NC;
  const int l = threadIdx.x;
  const int g = l >> 4;
  const int rr = l & 15;
  const int jc = (l < NN) ? l : (NN - 1);
  const float FSCALE = 1.0f / 48.0f;

  // ---- static A = E^T/48 with label map phi; A_log[i][k] = exp(trans[k*48+i])/48
  bf16x8 Af0[3], Af1[3];
  #pragma unroll
  for (int mt = 0; mt < 3; ++mt) {
    const int i = 16 * mt + rr;
    bf16x8 a0, a1;
    #pragma unroll
    for (int e = 0; e < 8; ++e) {
      int k0 = 16 * (e >> 2) + 4 * g + (e & 3);          // phi for K-tile 0
      a0[e] = (short)f2bf(__expf(trans[k0 * NN + i]) * FSCALE);
      int k1 = 32 + 4 * g + e;                           // phi for K-tile 1 (e<4)
      a1[e] = (e < 4) ? (short)f2bf(__expf(trans[k1 * NN + i]) * FSCALE) : (short)0;
    }
    Af0[mt] = a0; Af1[mt] = a1;
  }

  // ---- state: Y = I in pk encoding. pk0[mt][nt] = rows(16mt+4g, +1) of col 16nt+rr
  int pk0[3][3], pk1[3][3];
  #pragma unroll
  for (int mt = 0; mt < 3; ++mt)
  #pragma unroll
  for (int nt = 0; nt < 3; ++nt) {
    int r0 = 16 * mt + 4 * g, col = 16 * nt + rr;
    pk0[mt][nt] = ((r0     == col) ? 0x3F80 : 0) | (((r0 + 1 == col) ? 0x3F80 : 0) << 16);
    pk1[mt][nt] = ((r0 + 2 == col) ? 0x3F80 : 0) | (((r0 + 3 == col) ? 0x3F80 : 0) << 16);
  }

  const float* embr = em + (size_t)b * TT * NN + jc;
  const int t0 = c * CL + 1;
  const int count = (c == NC - 1) ? (CL - 1) : CL;
  const int wbase = g << 4;  // byte idx of lane 4g

  float pf0 = embr[(size_t)(t0 + 0) * NN];
  float pf1 = embr[(size_t)(t0 + 1) * NN];
  float pf2 = embr[(size_t)(t0 + 2) * NN];
  float pf3 = embr[(size_t)(t0 + 3) * NN];

  #define STEP(PF, NEXT_T) do {                                               \
    float w_ = __expf(PF);                                                    \
    int nt_ = (NEXT_T) > (TT - 1) ? (TT - 1) : (NEXT_T);                      \
    PF = embr[(size_t)nt_ * NN];                                              \
    int wi_ = __float_as_int(w_);                                             \
    v2f wv_[3][2];                                                            \
    _Pragma("unroll") for (int mt = 0; mt < 3; ++mt)                          \
    _Pragma("unroll") for (int h = 0; h < 2; ++h) {                           \
      int wa = bperm(wbase + mt * 64 + (2 * h) * 4, wi_);                     \
      int wb = bperm(wbase + mt * 64 + (2 * h + 1) * 4, wi_);                 \
      v2f t; t.x = __uint_as_float((unsigned)wa);                             \
      t.y = __uint_as_float((unsigned)wb); wv_[mt][h] = t;                    \
    }                                                                         \
    i32x4 B0v[3], B1v[3];                                                     \
    _Pragma("unroll") for (int nt = 0; nt < 3; ++nt) {                        \
      i32x4 b0; b0[0]=pk0[0][nt]; b0[1]=pk1[0][nt]; b0[2]=pk0[1][nt]; b0[3]=pk1[1][nt]; \
      i32x4 b1; b1[0]=pk0[2][nt]; b1[1]=pk1[2][nt]; b1[2]=0; b1[3]=0;         \
      B0v[nt] = b0; B1v[nt] = b1;                                             \
    }                                                                         \
    f32x4 acc_[3][3];                                                         \
    _Pragma("unroll") for (int mt = 0; mt < 3; ++mt)                          \
    _Pragma("unroll") for (int nt = 0; nt < 3; ++nt) {                        \
      f32x4 z = {0.f, 0.f, 0.f, 0.f};                                         \
      z = __builtin_amdgcn_mfma_f32_16x16x32_bf16(                            \
            Af0[mt], __builtin_bit_cast(bf16x8, B0v[nt]), z, 0, 0, 0);        \
      z = __builtin_amdgcn_mfma_f32_16x16x32_bf16(                            \
            Af1[mt], __builtin_bit_cast(bf16x8, B1v[nt]), z, 0, 0, 0);        \
      acc_[mt][nt] = z;                                                       \
    }                                                                         \
    _Pragma("unroll") for (int mt = 0; mt < 3; ++mt)                          \
    _Pragma("unroll") for (int nt = 0; nt < 3; ++nt) {                        \
      v2f lo; lo.x = acc_[mt][nt][0]; lo.y = acc_[mt][nt][1];                 \
      v2f hi; hi.x = acc_[mt][nt][2]; hi.y = acc_[mt][nt][3];                 \
      lo = lo * wv_[mt][0]; hi = hi * wv_[mt][1];                             \
      pk0[mt][nt] = cvt_pk_bf16(lo.x, lo.y);                                  \
      pk1[mt][nt] = cvt_pk_bf16(hi.x, hi.y);                                  \
    }                                                                         \
  } while (0)

  int t = t0;
  #pragma unroll 1
  for (int it = 0; it < count / 4; ++it) {
    STEP(pf0, t + 4);
    STEP(pf1, t + 5);
    STEP(pf2, t + 6);
    STEP(pf3, t + 7);
    t += 4;
  }
  if (count & 3) {  // last chunk: 3 remaining steps
    STEP(pf0, TT - 1);
    STEP(pf1, TT - 1);
    STEP(pf2, TT - 1);
  }
  #undef STEP

  // ---- store G[i][j] = Y[j][i], row-major bf16 [48][48]; j-pairs contiguous
  unsigned short* Gc = G + (size_t)blk * (NN * NN);
  #pragma unroll
  for (int mt = 0; mt < 3; ++mt)
  #pragma unroll
  for (int nt = 0; nt < 3; ++nt) {
    i32x2 d; d[0] = pk0[mt][nt]; d[1] = pk1[mt][nt];
    *(i32x2*)(Gc + (16 * nt + rr) * NN + 16 * mt + 4 * g) = d;
  }

  // ---- gold-score partial for seq slice [c*TT/NC, (c+1)*TT/NC)
  const int* tgb = tags + (size_t)b * TT;
  const float* emb = em + (size_t)b * TT * NN;
  float sc = 0.0f;
  const int base = c * (TT / NC);
  #pragma unroll
  for (int q = 0; q < TT / NC; q += 64) {
    int tt = base + q + l;
    int tg = tgb[tt];
    sc += emb[(size_t)tt * NN + tg];
    if (tt > 0) sc += trans[tgb[tt - 1] * NN + tg];
  }
  sc = wave_reduce_sum(sc);
  if (l == 0) sc_part[blk] = sc;
}

// ---------------- Phase 2: combine chunk products + finalize ------------
template<int NC>
__launch_bounds__(64, 1)
__global__ void crf_combine_kernel(const float* __restrict__ em,
                                   const float* __restrict__ startv,
                                   const float* __restrict__ endv,
                                   const int* __restrict__ tags,
                                   const unsigned short* __restrict__ G,
                                   const float* __restrict__ sc_part,
                                   float* __restrict__ out) {
  const int b = blockIdx.x;
  const int l = threadIdx.x;
  const int jc = (l < NN) ? l : (NN - 1);
  const float* emb = em + (size_t)b * TT * NN;
  const float FSCALE = 1.0f / 48.0f;

  float r = __expf(startv[jc] + emb[jc]);

  #pragma unroll 1
  for (int c = 0; c < NC; ++c) {
    const unsigned short* Gc = G + (size_t)(b * NC + c) * (NN * NN);
    float s0 = 0.f, s1 = 0.f, s2 = 0.f, s3 = 0.f;
    #pragma unroll
    for (int i = 0; i < NN; i += 4) {
      float g0 = __uint_as_float(((unsigned)Gc[(i + 0) * NN + jc]) << 16);
      float g1 = __uint_as_float(((unsigned)Gc[(i + 1) * NN + jc]) << 16);
      float g2 = __uint_as_float(((unsigned)Gc[(i + 2) * NN + jc]) << 16);
      float g3 = __uint_as_float(((unsigned)Gc[(i + 3) * NN + jc]) << 16);
      s0 = fmaf(lane_bcast(r, i + 0), g0, s0);
      s1 = fmaf(lane_bcast(r, i + 1), g1, s1);
      s2 = fmaf(lane_bcast(r, i + 2), g2, s2);
      s3 = fmaf(lane_bcast(r, i + 3), g3, s3);
    }
    r = (s0 + s1) + (s2 + s3);
  }

  float S = wave_reduce_sum((l < NN) ? r * __expf(endv[jc]) : 0.0f);
  float scp = wave_reduce_sum((l < NC) ? sc_part[b * NC + l] : 0.0f);

  if (l == 0) {
    const int* tgb = tags + (size_t)b * TT;
    double K = -log((double)FSCALE);  // exact -ln(float(1/48))
    double logZ = log((double)S) + 4095.0 * K;
    double score = (double)scp + (double)startv[tgb[0]] + (double)endv[tgb[TT - 1]];
    out[b] = (float)(logZ - score);
  }
}

extern "C" void kernel_launch(void* const* d_in, const int* in_sizes, int n_in,
                              void* d_out, int out_size, void* d_ws, size_t ws_size,
                              hipStream_t stream) {
  const float* em     = (const float*)d_in[0];
  const float* trans  = (const float*)d_in[1];
  const float* startv = (const float*)d_in[2];
  const float* endv   = (const float*)d_in[3];
  const int*   tags   = (const int*)d_in[4];
  float* out = (float*)d_out;

  // ws: [G: BB*NC*48*48 bf16][sc_part: BB*NC f32]
  const size_t need32 = (size_t)BB * 32 * NN * NN * 2 + (size_t)BB * 32 * 4;
  if (ws_size >= need32) {
    constexpr int NC = 32, CL = TT / 32;
    unsigned short* G = (unsigned short*)d_ws;
    float* sc_part = (float*)((char*)d_ws + (size_t)BB * NC * NN * NN * 2);
    hipLaunchKernelGGL((crf_chunk_kernel<NC, CL>), dim3(BB * NC), dim3(64), 0, stream,
                       em, trans, tags, G, sc_part);
    hipLaunchKernelGGL((crf_combine_kernel<NC>), dim3(BB), dim3(64), 0, stream,
                       em, startv, endv, tags, G, sc_part, out);
  } else {
    constexpr int NC = 16, CL = TT / 16;
    unsigned short* G = (unsigned short*)d_ws;
    float* sc_part = (float*)((char*)d_ws + (size_t)BB * NC * NN * NN * 2);
    hipLaunchKernelGGL((crf_chunk_kernel<NC, CL>), dim3(BB * NC), dim3(64), 0, stream,
                       em, trans, tags, G, sc_part);
    hipLaunchKernelGGL((crf_combine_kernel<NC>), dim3(BB), dim3(64), 0, stream,
                       em, startv, endv, tags, G, sc_part, out);
  }
}

// Round 5
// 136.375 us; speedup vs baseline: 7.5408x; 1.0368x over previous
//
#include <hip/hip_runtime.h>
#include <cmath>

#define BB 128
#define TT 4096
#define NN 48

typedef short bf16x8 __attribute__((ext_vector_type(8)));
typedef float f32x4 __attribute__((ext_vector_type(4)));
typedef int   i32x4 __attribute__((ext_vector_type(4)));
typedef int   i32x2 __attribute__((ext_vector_type(2)));

__device__ __forceinline__ float wave_reduce_sum(float v) {
  #pragma unroll
  for (int m = 32; m >= 1; m >>= 1) v += __shfl_xor(v, m, 64);
  return v;
}
__device__ __forceinline__ int bperm(int byteidx, int src) {
  return __builtin_amdgcn_ds_bpermute(byteidx, src);
}
__device__ __forceinline__ float lane_bcast(float x, int lane) {
  return __uint_as_float((unsigned)__builtin_amdgcn_readlane(__float_as_int(x), lane));
}
__device__ __forceinline__ int cvt_pk_bf16(float lo, float hi) {
  int r;
  asm("v_cvt_pk_bf16_f32 %0, %1, %2" : "=v"(r) : "v"(lo), "v"(hi));
  return r;
}
__device__ __forceinline__ unsigned short f2bf(float f) {  // RNE f32->bf16
  unsigned u = __float_as_uint(f);
  unsigned r = (u + 0x7FFFu + ((u >> 16) & 1u)) >> 16;
  return (unsigned short)r;
}

// ---------------- Phase 1: per-(batch,chunk) transition-matrix product ----
// One wave per (b,c). Chain Y <- diag(w_t) * E^T * Y  (Y as MFMA B-operand,
// static A = E^T/48), with the K-space relabel phi so the C-fragment's packed
// bf16 words ARE the next B-operand verbatim (verified R4, absmax 0.0).
// R5 restructure: B-quads are the PERSISTENT named state; cvt_pk writes quad
// elements in place (static indices); w-multiply reads MFMA acc elements as
// scalars. No vector-building temporaries -> no per-step register moves.
template<int NC, int CL>
__launch_bounds__(64, 4)
__global__ void crf_chunk_kernel(const float* __restrict__ em,
                                 const float* __restrict__ trans,
                                 const int* __restrict__ tags,
                                 unsigned short* __restrict__ G,
                                 float* __restrict__ sc_part) {
  const int blk = blockIdx.x;
  const int b = blk / NC;
  const int c = blk % NC;
  const int l = threadIdx.x;
  const int g = l >> 4;
  const int rr = l & 15;
  const int jc = (l < NN) ? l : (NN - 1);
  const float FSCALE = 1.0f / 48.0f;

  // ---- static A = E^T/48 with label map phi; A_log[i][k] = exp(trans[k*48+i])/48
  bf16x8 Af0[3], Af1[3];
  #pragma unroll
  for (int mt = 0; mt < 3; ++mt) {
    const int i = 16 * mt + rr;
    bf16x8 a0, a1;
    #pragma unroll
    for (int e = 0; e < 8; ++e) {
      int k0 = 16 * (e >> 2) + 4 * g + (e & 3);          // phi for K-tile 0
      a0[e] = (short)f2bf(__expf(trans[k0 * NN + i]) * FSCALE);
      int k1 = 32 + 4 * g + e;                           // phi for K-tile 1 (e<4)
      a1[e] = (e < 4) ? (short)f2bf(__expf(trans[k1 * NN + i]) * FSCALE) : (short)0;
    }
    Af0[mt] = a0; Af1[mt] = a1;
  }

  // ---- persistent state: Y = I in B-quad encoding.
  // B0s[nt] words: w -> rows (16*(w>>1) + 4g + 2*(w&1)) pair, col 16nt+rr
  // B1s[nt] words 0,1 -> rows (32 + 4g + 2w) pair; words 2,3 stay 0 forever.
  i32x4 B0s[3], B1s[3];
  #pragma unroll
  for (int nt = 0; nt < 3; ++nt) {
    const int col = 16 * nt + rr;
    i32x4 b0, b1;
    #pragma unroll
    for (int w = 0; w < 4; ++w) {
      int r0 = 16 * (w >> 1) + 4 * g + 2 * (w & 1);
      b0[w] = ((r0 == col) ? 0x3F80 : 0) | (((r0 + 1 == col) ? 0x3F80 : 0) << 16);
    }
    b1[0] = ((32 + 4 * g == col) ? 0x3F80 : 0) | (((33 + 4 * g == col) ? 0x3F80 : 0) << 16);
    b1[1] = ((34 + 4 * g == col) ? 0x3F80 : 0) | (((35 + 4 * g == col) ? 0x3F80 : 0) << 16);
    b1[2] = 0; b1[3] = 0;
    B0s[nt] = b0; B1s[nt] = b1;
  }

  const f32x4 zq = {0.f, 0.f, 0.f, 0.f};

  const float* embr = em + (size_t)b * TT * NN + jc;
  const int t0 = c * CL + 1;
  const int count = (c == NC - 1) ? (CL - 1) : CL;
  const int wbyte = g << 4;  // byte idx of lane 4g

  // 8-deep emission prefetch (named registers)
  float pf0 = embr[(size_t)(t0 + 0) * NN];
  float pf1 = embr[(size_t)(t0 + 1) * NN];
  float pf2 = embr[(size_t)(t0 + 2) * NN];
  float pf3 = embr[(size_t)(t0 + 3) * NN];
  float pf4 = embr[(size_t)(t0 + 4) * NN];
  float pf5 = embr[(size_t)(t0 + 5) * NN];
  float pf6 = embr[(size_t)(t0 + 6) * NN];
  float pf7 = embr[(size_t)(t0 + 7) * NN];

  #define STEP(PF, NEXT_T) do {                                               \
    float w_ = __expf(PF);                                                    \
    int nxt_ = (NEXT_T) > (TT - 1) ? (TT - 1) : (NEXT_T);                     \
    PF = embr[(size_t)nxt_ * NN];                                             \
    int wi_ = __float_as_int(w_);                                             \
    float wb_[12];                                                            \
    _Pragma("unroll") for (int mt = 0; mt < 3; ++mt)                          \
    _Pragma("unroll") for (int r = 0; r < 4; ++r)                             \
      wb_[mt * 4 + r] =                                                       \
          __uint_as_float((unsigned)bperm(wbyte + mt * 64 + r * 4, wi_));     \
    _Pragma("unroll") for (int nt = 0; nt < 3; ++nt) {                        \
      f32x4 a0_ = __builtin_amdgcn_mfma_f32_16x16x32_bf16(                    \
          Af0[0], __builtin_bit_cast(bf16x8, B0s[nt]), zq, 0, 0, 0);          \
      f32x4 a1_ = __builtin_amdgcn_mfma_f32_16x16x32_bf16(                    \
          Af0[1], __builtin_bit_cast(bf16x8, B0s[nt]), zq, 0, 0, 0);          \
      f32x4 a2_ = __builtin_amdgcn_mfma_f32_16x16x32_bf16(                    \
          Af0[2], __builtin_bit_cast(bf16x8, B0s[nt]), zq, 0, 0, 0);          \
      a0_ = __builtin_amdgcn_mfma_f32_16x16x32_bf16(                          \
          Af1[0], __builtin_bit_cast(bf16x8, B1s[nt]), a0_, 0, 0, 0);         \
      a1_ = __builtin_amdgcn_mfma_f32_16x16x32_bf16(                          \
          Af1[1], __builtin_bit_cast(bf16x8, B1s[nt]), a1_, 0, 0, 0);         \
      a2_ = __builtin_amdgcn_mfma_f32_16x16x32_bf16(                          \
          Af1[2], __builtin_bit_cast(bf16x8, B1s[nt]), a2_, 0, 0, 0);         \
      B0s[nt][0] = cvt_pk_bf16(a0_[0] * wb_[0],  a0_[1] * wb_[1]);            \
      B0s[nt][1] = cvt_pk_bf16(a0_[2] * wb_[2],  a0_[3] * wb_[3]);            \
      B0s[nt][2] = cvt_pk_bf16(a1_[0] * wb_[4],  a1_[1] * wb_[5]);            \
      B0s[nt][3] = cvt_pk_bf16(a1_[2] * wb_[6],  a1_[3] * wb_[7]);            \
      B1s[nt][0] = cvt_pk_bf16(a2_[0] * wb_[8],  a2_[1] * wb_[9]);            \
      B1s[nt][1] = cvt_pk_bf16(a2_[2] * wb_[10], a2_[3] * wb_[11]);           \
    }                                                                         \
  } while (0)

  int t = t0;
  #pragma unroll 1
  for (int it = 0; it < count / 8; ++it) {
    STEP(pf0, t + 8);
    STEP(pf1, t + 9);
    STEP(pf2, t + 10);
    STEP(pf3, t + 11);
    STEP(pf4, t + 12);
    STEP(pf5, t + 13);
    STEP(pf6, t + 14);
    STEP(pf7, t + 15);
    t += 8;
  }
  if (count & 7) {  // last chunk: 7 remaining steps
    STEP(pf0, TT - 1);
    STEP(pf1, TT - 1);
    STEP(pf2, TT - 1);
    STEP(pf3, TT - 1);
    STEP(pf4, TT - 1);
    STEP(pf5, TT - 1);
    STEP(pf6, TT - 1);
  }
  #undef STEP

  // ---- store G[i][j] = Y[j][i], row-major bf16 [48][48]; j-pairs contiguous
  // pk0[mt][nt]: mt=0 -> B0s[nt][0], mt=1 -> B0s[nt][2], mt=2 -> B1s[nt][0]
  // pk1[mt][nt]: mt=0 -> B0s[nt][1], mt=1 -> B0s[nt][3], mt=2 -> B1s[nt][1]
  unsigned short* Gc = G + (size_t)blk * (NN * NN);
  #pragma unroll
  for (int nt = 0; nt < 3; ++nt) {
    const int rowoff = (16 * nt + rr) * NN + 4 * g;
    i32x2 d0; d0[0] = B0s[nt][0]; d0[1] = B0s[nt][1];
    i32x2 d1; d1[0] = B0s[nt][2]; d1[1] = B0s[nt][3];
    i32x2 d2; d2[0] = B1s[nt][0]; d2[1] = B1s[nt][1];
    *(i32x2*)(Gc + rowoff)      = d0;
    *(i32x2*)(Gc + rowoff + 16) = d1;
    *(i32x2*)(Gc + rowoff + 32) = d2;
  }

  // ---- gold-score partial for seq slice [c*TT/NC, (c+1)*TT/NC)
  const int* tgb = tags + (size_t)b * TT;
  const float* emb = em + (size_t)b * TT * NN;
  float sc = 0.0f;
  const int base = c * (TT / NC);
  #pragma unroll
  for (int q = 0; q < TT / NC; q += 64) {
    int tt = base + q + l;
    int tg = tgb[tt];
    sc += emb[(size_t)tt * NN + tg];
    if (tt > 0) sc += trans[tgb[tt - 1] * NN + tg];
  }
  sc = wave_reduce_sum(sc);
  if (l == 0) sc_part[blk] = sc;
}

// ---------------- Phase 2: combine chunk products + finalize ------------
template<int NC>
__launch_bounds__(64, 1)
__global__ void crf_combine_kernel(const float* __restrict__ em,
                                   const float* __restrict__ startv,
                                   const float* __restrict__ endv,
                                   const int* __restrict__ tags,
                                   const unsigned short* __restrict__ G,
                                   const float* __restrict__ sc_part,
                                   float* __restrict__ out) {
  const int b = blockIdx.x;
  const int l = threadIdx.x;
  const int jc = (l < NN) ? l : (NN - 1);
  const float* emb = em + (size_t)b * TT * NN;
  const float FSCALE = 1.0f / 48.0f;

  float r = __expf(startv[jc] + emb[jc]);

  #pragma unroll 1
  for (int c = 0; c < NC; ++c) {
    const unsigned short* Gc = G + (size_t)(b * NC + c) * (NN * NN);
    float s0 = 0.f, s1 = 0.f, s2 = 0.f, s3 = 0.f;
    #pragma unroll
    for (int i = 0; i < NN; i += 4) {
      float g0 = __uint_as_float(((unsigned)Gc[(i + 0) * NN + jc]) << 16);
      float g1 = __uint_as_float(((unsigned)Gc[(i + 1) * NN + jc]) << 16);
      float g2 = __uint_as_float(((unsigned)Gc[(i + 2) * NN + jc]) << 16);
      float g3 = __uint_as_float(((unsigned)Gc[(i + 3) * NN + jc]) << 16);
      s0 = fmaf(lane_bcast(r, i + 0), g0, s0);
      s1 = fmaf(lane_bcast(r, i + 1), g1, s1);
      s2 = fmaf(lane_bcast(r, i + 2), g2, s2);
      s3 = fmaf(lane_bcast(r, i + 3), g3, s3);
    }
    r = (s0 + s1) + (s2 + s3);
  }

  float S = wave_reduce_sum((l < NN) ? r * __expf(endv[jc]) : 0.0f);
  float scp = wave_reduce_sum((l < NC) ? sc_part[b * NC + l] : 0.0f);

  if (l == 0) {
    const int* tgb = tags + (size_t)b * TT;
    double K = -log((double)FSCALE);  // exact -ln(float(1/48))
    double logZ = log((double)S) + 4095.0 * K;
    double score = (double)scp + (double)startv[tgb[0]] + (double)endv[tgb[TT - 1]];
    out[b] = (float)(logZ - score);
  }
}

extern "C" void kernel_launch(void* const* d_in, const int* in_sizes, int n_in,
                              void* d_out, int out_size, void* d_ws, size_t ws_size,
                              hipStream_t stream) {
  const float* em     = (const float*)d_in[0];
  const float* trans  = (const float*)d_in[1];
  const float* startv = (const float*)d_in[2];
  const float* endv   = (const float*)d_in[3];
  const int*   tags   = (const int*)d_in[4];
  float* out = (float*)d_out;

  // ws: [G: BB*NC*48*48 bf16][sc_part: BB*NC f32]
  const size_t need32 = (size_t)BB * 32 * NN * NN * 2 + (size_t)BB * 32 * 4;
  if (ws_size >= need32) {
    constexpr int NC = 32, CL = TT / 32;
    unsigned short* G = (unsigned short*)d_ws;
    float* sc_part = (float*)((char*)d_ws + (size_t)BB * NC * NN * NN * 2);
    hipLaunchKernelGGL((crf_chunk_kernel<NC, CL>), dim3(BB * NC), dim3(64), 0, stream,
                       em, trans, tags, G, sc_part);
    hipLaunchKernelGGL((crf_combine_kernel<NC>), dim3(BB), dim3(64), 0, stream,
                       em, startv, endv, tags, G, sc_part, out);
  } else {
    constexpr int NC = 16, CL = TT / 16;
    unsigned short* G = (unsigned short*)d_ws;
    float* sc_part = (float*)((char*)d_ws + (size_t)BB * NC * NN * NN * 2);
    hipLaunchKernelGGL((crf_chunk_kernel<NC, CL>), dim3(BB * NC), dim3(64), 0, stream,
                       em, trans, tags, G, sc_part);
    hipLaunchKernelGGL((crf_combine_kernel<NC>), dim3(BB), dim3(64), 0, stream,
                       em, startv, endv, tags, G, sc_part, out);
  }
}

// Round 6
// 123.541 us; speedup vs baseline: 8.3242x; 1.1039x over previous
//
#include <hip/hip_runtime.h>
#include <cmath>

#define BB 128
#define TT 4096
#define NN 48

typedef short bf16x8 __attribute__((ext_vector_type(8)));
typedef short bf16x4 __attribute__((ext_vector_type(4)));
typedef float f32x4 __attribute__((ext_vector_type(4)));
typedef int   i32x4 __attribute__((ext_vector_type(4)));
typedef int   i32x2 __attribute__((ext_vector_type(2)));

__device__ __forceinline__ float wave_reduce_sum(float v) {
  #pragma unroll
  for (int m = 32; m >= 1; m >>= 1) v += __shfl_xor(v, m, 64);
  return v;
}
__device__ __forceinline__ int bperm(int byteidx, int src) {
  return __builtin_amdgcn_ds_bpermute(byteidx, src);
}
__device__ __forceinline__ float lane_bcast(float x, int lane) {
  return __uint_as_float((unsigned)__builtin_amdgcn_readlane(__float_as_int(x), lane));
}
__device__ __forceinline__ int cvt_pk_bf16(float lo, float hi) {
  int r;
  asm("v_cvt_pk_bf16_f32 %0, %1, %2" : "=v"(r) : "v"(lo), "v"(hi));
  return r;
}
__device__ __forceinline__ unsigned short f2bf(float f) {  // RNE f32->bf16
  unsigned u = __float_as_uint(f);
  unsigned r = (u + 0x7FFFu + ((u >> 16) & 1u)) >> 16;
  return (unsigned short)r;
}

// ---------------- Phase 1: per-(batch,chunk) transition-matrix product ----
// One wave per (b,c). Chain Y <- diag(w_t) * E^T * Y  (Y as MFMA B-operand,
// static A = E^T/48), with the K-space relabel so the C-fragment's packed
// bf16 words ARE the next B-operand verbatim (verified R4/R5, absmax 0.0).
// R6: (1) waves_per_eu(4,4) -> 128-VGPR budget, no AGPR round-trips;
//     (2) K=48 split as one 16x16x32 (rows 0..31, label phi) plus one
//         16x16x16 (rows 32..47, label psi(g,e)=32+4g+e) -> no zero-padding;
//     (3) pointer-increment emission prefetch (no per-step 64-bit mul).
template<int NC, int CL>
__global__ __launch_bounds__(64) __attribute__((amdgpu_waves_per_eu(4, 4)))
void crf_chunk_kernel(const float* __restrict__ em,
                      const float* __restrict__ trans,
                      const int* __restrict__ tags,
                      unsigned short* __restrict__ G,
                      float* __restrict__ sc_part) {
  const int blk = blockIdx.x;
  const int b = blk / NC;
  const int c = blk % NC;
  const int l = threadIdx.x;
  const int g = l >> 4;
  const int rr = l & 15;
  const int jc = (l < NN) ? l : (NN - 1);
  const float FSCALE = 1.0f / 48.0f;

  // ---- static A = E^T/48. K-tile0 (16x16x32): label phi(g,e)=16*(e>>2)+4g+(e&3)
  //      K-tile1 (16x16x16): label psi(g,e)=32+4g+e
  bf16x8 Af0[3];
  bf16x4 Af1[3];
  #pragma unroll
  for (int mt = 0; mt < 3; ++mt) {
    const int i = 16 * mt + rr;
    bf16x8 a0;
    bf16x4 a1;
    #pragma unroll
    for (int e = 0; e < 8; ++e) {
      int k0 = 16 * (e >> 2) + 4 * g + (e & 3);
      a0[e] = (short)f2bf(__expf(trans[k0 * NN + i]) * FSCALE);
    }
    #pragma unroll
    for (int e = 0; e < 4; ++e) {
      int k1 = 32 + 4 * g + e;
      a1[e] = (short)f2bf(__expf(trans[k1 * NN + i]) * FSCALE);
    }
    Af0[mt] = a0; Af1[mt] = a1;
  }

  // ---- persistent state: Y = I in B-quad encoding.
  // B0s[nt] word w -> rows (16*(w>>1) + 4g + 2*(w&1), +1), col 16nt+rr
  // B1s[nt] word w -> rows (32 + 4g + 2w, +1)
  i32x4 B0s[3];
  i32x2 B1s[3];
  #pragma unroll
  for (int nt = 0; nt < 3; ++nt) {
    const int col = 16 * nt + rr;
    i32x4 b0;
    i32x2 b1;
    #pragma unroll
    for (int w = 0; w < 4; ++w) {
      int r0 = 16 * (w >> 1) + 4 * g + 2 * (w & 1);
      b0[w] = ((r0 == col) ? 0x3F80 : 0) | (((r0 + 1 == col) ? 0x3F80 : 0) << 16);
    }
    #pragma unroll
    for (int w = 0; w < 2; ++w) {
      int r0 = 32 + 4 * g + 2 * w;
      b1[w] = ((r0 == col) ? 0x3F80 : 0) | (((r0 + 1 == col) ? 0x3F80 : 0) << 16);
    }
    B0s[nt] = b0; B1s[nt] = b1;
  }

  const f32x4 zq = {0.f, 0.f, 0.f, 0.f};

  const float* embr = em + (size_t)b * TT * NN + jc;
  const int t0 = c * CL + 1;
  const int wbyte = g << 4;  // byte idx of lane 4g

  // 8-deep emission prefetch (named registers)
  float pf0 = embr[(size_t)(t0 + 0) * NN];
  float pf1 = embr[(size_t)(t0 + 1) * NN];
  float pf2 = embr[(size_t)(t0 + 2) * NN];
  float pf3 = embr[(size_t)(t0 + 3) * NN];
  float pf4 = embr[(size_t)(t0 + 4) * NN];
  float pf5 = embr[(size_t)(t0 + 5) * NN];
  float pf6 = embr[(size_t)(t0 + 6) * NN];
  float pf7 = embr[(size_t)(t0 + 7) * NN];

  // core of one step, given w already in wi_
  #define BODY() do {                                                         \
    float wb_[12];                                                            \
    _Pragma("unroll") for (int mt = 0; mt < 3; ++mt)                          \
    _Pragma("unroll") for (int r = 0; r < 4; ++r)                             \
      wb_[mt * 4 + r] =                                                       \
          __uint_as_float((unsigned)bperm(wbyte + mt * 64 + r * 4, wi_));     \
    _Pragma("unroll") for (int nt = 0; nt < 3; ++nt) {                        \
      bf16x4 b1c_ = __builtin_bit_cast(bf16x4, B1s[nt]);                      \
      bf16x8 b0c_ = __builtin_bit_cast(bf16x8, B0s[nt]);                      \
      f32x4 a0_ = __builtin_amdgcn_mfma_f32_16x16x16bf16_1k(Af1[0], b1c_, zq, 0, 0, 0); \
      f32x4 a1_ = __builtin_amdgcn_mfma_f32_16x16x16bf16_1k(Af1[1], b1c_, zq, 0, 0, 0); \
      f32x4 a2_ = __builtin_amdgcn_mfma_f32_16x16x16bf16_1k(Af1[2], b1c_, zq, 0, 0, 0); \
      a0_ = __builtin_amdgcn_mfma_f32_16x16x32_bf16(Af0[0], b0c_, a0_, 0, 0, 0); \
      a1_ = __builtin_amdgcn_mfma_f32_16x16x32_bf16(Af0[1], b0c_, a1_, 0, 0, 0); \
      a2_ = __builtin_amdgcn_mfma_f32_16x16x32_bf16(Af0[2], b0c_, a2_, 0, 0, 0); \
      B0s[nt][0] = cvt_pk_bf16(a0_[0] * wb_[0],  a0_[1] * wb_[1]);            \
      B0s[nt][1] = cvt_pk_bf16(a0_[2] * wb_[2],  a0_[3] * wb_[3]);            \
      B0s[nt][2] = cvt_pk_bf16(a1_[0] * wb_[4],  a1_[1] * wb_[5]);            \
      B0s[nt][3] = cvt_pk_bf16(a1_[2] * wb_[6],  a1_[3] * wb_[7]);            \
      B1s[nt][0] = cvt_pk_bf16(a2_[0] * wb_[8],  a2_[1] * wb_[9]);            \
      B1s[nt][1] = cvt_pk_bf16(a2_[2] * wb_[10], a2_[3] * wb_[11]);           \
    }                                                                         \
  } while (0)

  // fast step: prefetch via pointer + folded immediate offset
  #define STEPF(PF, NPTR) do {                                                \
    float w_ = __expf(PF);                                                    \
    PF = *(NPTR);                                                             \
    int wi_ = __float_as_int(w_);                                             \
    BODY();                                                                   \
  } while (0)

  // clamped step: index form, only for the last chunk's tail
  #define STEPC(PF, NEXT_T) do {                                              \
    float w_ = __expf(PF);                                                    \
    int nxt_ = (NEXT_T) > (TT - 1) ? (TT - 1) : (NEXT_T);                     \
    PF = embr[(size_t)nxt_ * NN];                                             \
    int wi_ = __float_as_int(w_);                                             \
    BODY();                                                                   \
  } while (0)

  if (c != NC - 1) {
    // count = CL steps exactly; prefetch may read up to 8 rows into the next
    // chunk (in-bounds since c < NC-1).
    const float* pref = embr + (size_t)(t0 + 8) * NN;
    #pragma unroll 1
    for (int it = 0; it < CL / 8; ++it) {
      STEPF(pf0, pref + 0 * NN);
      STEPF(pf1, pref + 1 * NN);
      STEPF(pf2, pref + 2 * NN);
      STEPF(pf3, pref + 3 * NN);
      STEPF(pf4, pref + 4 * NN);
      STEPF(pf5, pref + 5 * NN);
      STEPF(pf6, pref + 6 * NN);
      STEPF(pf7, pref + 7 * NN);
      pref += 8 * NN;
    }
  } else {
    // count = CL-1 steps. Fast for CL/8 - 2 iterations (prefetch stays
    // within t0 + CL - 9 + 8 < TT), clamped-index for the remaining 15.
    const float* pref = embr + (size_t)(t0 + 8) * NN;
    #pragma unroll 1
    for (int it = 0; it < CL / 8 - 2; ++it) {
      STEPF(pf0, pref + 0 * NN);
      STEPF(pf1, pref + 1 * NN);
      STEPF(pf2, pref + 2 * NN);
      STEPF(pf3, pref + 3 * NN);
      STEPF(pf4, pref + 4 * NN);
      STEPF(pf5, pref + 5 * NN);
      STEPF(pf6, pref + 6 * NN);
      STEPF(pf7, pref + 7 * NN);
      pref += 8 * NN;
    }
    const int tb = t0 + CL - 16;  // pf0..pf7 currently hold rows tb..tb+7
    STEPC(pf0, tb + 8);
    STEPC(pf1, tb + 9);
    STEPC(pf2, tb + 10);
    STEPC(pf3, tb + 11);
    STEPC(pf4, tb + 12);
    STEPC(pf5, tb + 13);
    STEPC(pf6, tb + 14);
    STEPC(pf7, tb + 15);
    STEPC(pf0, tb + 16);
    STEPC(pf1, tb + 17);
    STEPC(pf2, tb + 18);
    STEPC(pf3, tb + 19);
    STEPC(pf4, tb + 20);
    STEPC(pf5, tb + 21);
    STEPC(pf6, tb + 22);
  }
  #undef STEPF
  #undef STEPC
  #undef BODY

  // ---- store G[i][j] = Y[j][i], row-major bf16 [48][48]; j-pairs contiguous
  unsigned short* Gc = G + (size_t)blk * (NN * NN);
  #pragma unroll
  for (int nt = 0; nt < 3; ++nt) {
    const int rowoff = (16 * nt + rr) * NN + 4 * g;
    i32x2 d0; d0[0] = B0s[nt][0]; d0[1] = B0s[nt][1];
    i32x2 d1; d1[0] = B0s[nt][2]; d1[1] = B0s[nt][3];
    i32x2 d2; d2[0] = B1s[nt][0]; d2[1] = B1s[nt][1];
    *(i32x2*)(Gc + rowoff)      = d0;
    *(i32x2*)(Gc + rowoff + 16) = d1;
    *(i32x2*)(Gc + rowoff + 32) = d2;
  }

  // ---- gold-score partial for seq slice [c*TT/NC, (c+1)*TT/NC)
  const int* tgb = tags + (size_t)b * TT;
  const float* emb = em + (size_t)b * TT * NN;
  float sc = 0.0f;
  const int base = c * (TT / NC);
  #pragma unroll
  for (int q = 0; q < TT / NC; q += 64) {
    int tt = base + q + l;
    int tg = tgb[tt];
    sc += emb[(size_t)tt * NN + tg];
    if (tt > 0) sc += trans[tgb[tt - 1] * NN + tg];
  }
  sc = wave_reduce_sum(sc);
  if (l == 0) sc_part[blk] = sc;
}

// ---------------- Phase 2: combine chunk products + finalize ------------
template<int NC>
__launch_bounds__(64, 1)
__global__ void crf_combine_kernel(const float* __restrict__ em,
                                   const float* __restrict__ startv,
                                   const float* __restrict__ endv,
                                   const int* __restrict__ tags,
                                   const unsigned short* __restrict__ G,
                                   const float* __restrict__ sc_part,
                                   float* __restrict__ out) {
  const int b = blockIdx.x;
  const int l = threadIdx.x;
  const int jc = (l < NN) ? l : (NN - 1);
  const float* emb = em + (size_t)b * TT * NN;
  const float FSCALE = 1.0f / 48.0f;

  float r = __expf(startv[jc] + emb[jc]);

  #pragma unroll 1
  for (int c = 0; c < NC; ++c) {
    const unsigned short* Gc = G + (size_t)(b * NC + c) * (NN * NN);
    float s0 = 0.f, s1 = 0.f, s2 = 0.f, s3 = 0.f;
    #pragma unroll
    for (int i = 0; i < NN; i += 4) {
      float g0 = __uint_as_float(((unsigned)Gc[(i + 0) * NN + jc]) << 16);
      float g1 = __uint_as_float(((unsigned)Gc[(i + 1) * NN + jc]) << 16);
      float g2 = __uint_as_float(((unsigned)Gc[(i + 2) * NN + jc]) << 16);
      float g3 = __uint_as_float(((unsigned)Gc[(i + 3) * NN + jc]) << 16);
      s0 = fmaf(lane_bcast(r, i + 0), g0, s0);
      s1 = fmaf(lane_bcast(r, i + 1), g1, s1);
      s2 = fmaf(lane_bcast(r, i + 2), g2, s2);
      s3 = fmaf(lane_bcast(r, i + 3), g3, s3);
    }
    r = (s0 + s1) + (s2 + s3);
  }

  float S = wave_reduce_sum((l < NN) ? r * __expf(endv[jc]) : 0.0f);
  float scp = wave_reduce_sum((l < NC) ? sc_part[b * NC + l] : 0.0f);

  if (l == 0) {
    const int* tgb = tags + (size_t)b * TT;
    double K = -log((double)FSCALE);  // exact -ln(float(1/48))
    double logZ = log((double)S) + 4095.0 * K;
    double score = (double)scp + (double)startv[tgb[0]] + (double)endv[tgb[TT - 1]];
    out[b] = (float)(logZ - score);
  }
}

extern "C" void kernel_launch(void* const* d_in, const int* in_sizes, int n_in,
                              void* d_out, int out_size, void* d_ws, size_t ws_size,
                              hipStream_t stream) {
  const float* em     = (const float*)d_in[0];
  const float* trans  = (const float*)d_in[1];
  const float* startv = (const float*)d_in[2];
  const float* endv   = (const float*)d_in[3];
  const int*   tags   = (const int*)d_in[4];
  float* out = (float*)d_out;

  // ws: [G: BB*NC*48*48 bf16][sc_part: BB*NC f32]
  const size_t need32 = (size_t)BB * 32 * NN * NN * 2 + (size_t)BB * 32 * 4;
  if (ws_size >= need32) {
    constexpr int NC = 32, CL = TT / 32;
    unsigned short* G = (unsigned short*)d_ws;
    float* sc_part = (float*)((char*)d_ws + (size_t)BB * NC * NN * NN * 2);
    hipLaunchKernelGGL((crf_chunk_kernel<NC, CL>), dim3(BB * NC), dim3(64), 0, stream,
                       em, trans, tags, G, sc_part);
    hipLaunchKernelGGL((crf_combine_kernel<NC>), dim3(BB), dim3(64), 0, stream,
                       em, startv, endv, tags, G, sc_part, out);
  } else {
    constexpr int NC = 16, CL = TT / 16;
    unsigned short* G = (unsigned short*)d_ws;
    float* sc_part = (float*)((char*)d_ws + (size_t)BB * NC * NN * NN * 2);
    hipLaunchKernelGGL((crf_chunk_kernel<NC, CL>), dim3(BB * NC), dim3(64), 0, stream,
                       em, trans, tags, G, sc_part);
    hipLaunchKernelGGL((crf_combine_kernel<NC>), dim3(BB), dim3(64), 0, stream,
                       em, startv, endv, tags, G, sc_part, out);
  }
}